// Round 2
// baseline (1470.319 us; speedup 1.0000x reference)
//
#include <hip/hip_runtime.h>
#include <math.h>

#define T_N 2048
#define H_N 2048
#define E_N 32
#define I_N 512
#define NA_MOE (T_N*4)        // 8192 routed assignments
#define NA_ALL (NA_MOE + T_N) // + shared-expert rows = 10240
#define BM 256
#define BK 32

typedef short s16x8 __attribute__((ext_vector_type(8)));
typedef float f32x4 __attribute__((ext_vector_type(4)));

__device__ inline short f2bf(float f){
    unsigned int u = __float_as_uint(f);
    u = (u + 0x7fffu + ((u >> 16) & 1u)) >> 16;
    return (short)u;
}

__device__ inline s16x8 cvt8(float4 f0, float4 f1){
    s16x8 v;
    v[0]=f2bf(f0.x); v[1]=f2bf(f0.y); v[2]=f2bf(f0.z); v[3]=f2bf(f0.w);
    v[4]=f2bf(f1.x); v[5]=f2bf(f1.y); v[6]=f2bf(f1.z); v[7]=f2bf(f1.w);
    return v;
}

// ---------------- cast x (fp32 -> bf16) ----------------
__global__ __launch_bounds__(256) void cast_x_kernel(const float* __restrict__ x,
                                                     short* __restrict__ xbf){
    size_t i = (size_t)(blockIdx.x * 256 + threadIdx.x) * 8;
    float4 a = *(const float4*)(x + i);
    float4 b = *(const float4*)(x + i + 4);
    *(s16x8*)(xbf + i) = cvt8(a, b);
}

// ---------------- router: logits (fp64 acc), softmax, top4, shared gate ----------------
__global__ __launch_bounds__(64) void router_kernel(
    const float* __restrict__ x, const float* __restrict__ Wr,
    const float* __restrict__ Wsgate,
    float* __restrict__ logits_out, int* __restrict__ tidx, float* __restrict__ tw,
    int* __restrict__ perm, float* __restrict__ wgt, int* __restrict__ counts)
{
    const int t = blockIdx.x, lane = threadIdx.x;
    const float* xr = x + (size_t)t * H_N;
    float xv[32];
    #pragma unroll
    for (int i = 0; i < 32; i++) xv[i] = xr[i*64 + lane];
    __shared__ float lg[34];
    for (int e = 0; e < 33; e++){
        const float* wr = (e < 32) ? (Wr + (size_t)e * H_N) : Wsgate;
        double s = 0.0;
        #pragma unroll
        for (int i = 0; i < 32; i++) s += (double)xv[i] * (double)wr[i*64 + lane];
        #pragma unroll
        for (int o = 32; o > 0; o >>= 1) s += __shfl_down(s, o);
        if (lane == 0) lg[e] = (float)s;
    }
    __syncthreads();
    if (lane < 32) logits_out[(size_t)t*32 + lane] = lg[lane];
    if (lane == 0){
        float m = lg[0];
        for (int e = 1; e < 32; e++) m = fmaxf(m, lg[e]);
        unsigned mask = 0; int sel[4]; float sv[4]; float s4 = 0.f;
        for (int k = 0; k < 4; k++){
            int best = -1; float bv = -1e30f;
            for (int e = 0; e < 32; e++)
                if (!((mask >> e) & 1u) && lg[e] > bv){ bv = lg[e]; best = e; }
            mask |= 1u << best; sel[k] = best;
            float p = expf(lg[best] - m); sv[k] = p; s4 += p;
        }
        for (int k = 0; k < 4; k++){
            tidx[t*4 + k] = sel[k];
            tw[t*4 + k]   = sv[k] / s4;
            atomicAdd(&counts[sel[k]], 1);
        }
        perm[NA_MOE + t] = t;                       // shared expert row
        wgt[NA_MOE + t]  = 1.f / (1.f + expf(-lg[32]));
    }
}

// ---------------- scan: offsets from counts ----------------
__global__ void scan_kernel(int* ctrl){
    if (threadIdx.x == 0){
        int* counts = ctrl; int* eoff = ctrl + 128; int* ecnt = ctrl + 192;
        int acc = 0;
        for (int e = 0; e < 32; e++){ eoff[e] = acc; ecnt[e] = counts[e]; acc += counts[e]; }
        eoff[32] = NA_MOE; ecnt[32] = T_N;
    }
    if (threadIdx.x < 64) ctrl[64 + threadIdx.x] = 0;  // cursors
}

// ---------------- scatter tokens into per-expert lists ----------------
__global__ __launch_bounds__(256) void scatter_kernel(
    const int* __restrict__ tidx, const float* __restrict__ tw,
    int* __restrict__ perm, float* __restrict__ wgt, int* ctrl)
{
    int t = blockIdx.x * 256 + threadIdx.x;
    if (t >= T_N) return;
    const int* eoff = ctrl + 128; int* cursor = ctrl + 64;
    for (int k = 0; k < 4; k++){
        int e = tidx[t*4 + k];
        int pos = eoff[e] + atomicAdd(&cursor[e], 1);
        perm[pos] = t; wgt[pos] = tw[t*4 + k];
    }
}

// ---------------- GEMM1: 256x64 tile, 8 waves. hact = silu(g)*u, bf16 out ----------------
__global__ __launch_bounds__(512) void gemm1_kernel(
    const short* __restrict__ xbf,
    const float* __restrict__ Wg, const float* __restrict__ Wu,
    const float* __restrict__ Wsg, const float* __restrict__ Wsu,
    const int* __restrict__ perm, const int* __restrict__ ctrl,
    short* __restrict__ hact)
{
    const int e   = blockIdx.y;
    const int cnt = ctrl[192 + e];
    const int m0  = blockIdx.x * BM;
    if (m0 >= cnt) return;
    const int off = ctrl[128 + e];
    const int n0  = blockIdx.z * 64;

    __shared__ s16x8 lsA[4*256];   // [kc][r]
    __shared__ s16x8 lsBg[4*64];
    __shared__ s16x8 lsBu[4*64];

    const int tid = threadIdx.x;
    // A staging: thread owns row r_a, k-chunks kca and kca+2
    const int r_a = tid & 255;
    const int kca = tid >> 8;      // 0/1
    const short* arow = nullptr;
    if (m0 + r_a < cnt) arow = xbf + (size_t)perm[off + m0 + r_a] * H_N;

    // B staging: tid<256 -> gate, tid>=256 -> up; chunk c = tid&255
    const int cb  = tid & 255;
    const int kcb = cb & 3, rb = cb >> 2;
    const float* brow;
    if (e < 32){
        const float* Wbase = (tid < 256) ? Wg : Wu;
        brow = Wbase + ((size_t)e * I_N + (n0 + rb)) * H_N + kcb*8;
    } else {
        const float* Wbase = (tid < 256) ? Wsg : Wsu;
        brow = Wbase + (size_t)(n0 + rb) * H_N + kcb*8;
    }
    s16x8* lsBmine = (tid < 256) ? lsBg : lsBu;

    const int wid = tid >> 6, lane = tid & 63;
    const int wm = wid >> 1, wn = wid & 1;       // 4m x 2n waves
    const int kg = lane >> 4, l15 = lane & 15;

    f32x4 accg[4][2], accu[4][2];
    #pragma unroll
    for (int a = 0; a < 4; a++)
        #pragma unroll
        for (int b = 0; b < 2; b++)
            #pragma unroll
            for (int j = 0; j < 4; j++){ accg[a][b][j] = 0.f; accu[a][b][j] = 0.f; }

    for (int k0 = 0; k0 < H_N; k0 += BK){
        s16x8 a0{}, a1{};
        if (arow){
            a0 = *(const s16x8*)(arow + k0 + kca*8);
            a1 = *(const s16x8*)(arow + k0 + (kca+2)*8);
        }
        const float* p = brow + k0;
        float4 f0 = *(const float4*)p;
        float4 f1 = *(const float4*)(p + 4);
        __syncthreads();
        lsA[kca*256 + r_a]     = a0;
        lsA[(kca+2)*256 + r_a] = a1;
        lsBmine[kcb*64 + rb]   = cvt8(f0, f1);
        __syncthreads();
        s16x8 bg[2], bu[2];
        #pragma unroll
        for (int nf = 0; nf < 2; nf++){
            bg[nf] = lsBg[kg*64 + wn*32 + nf*16 + l15];
            bu[nf] = lsBu[kg*64 + wn*32 + nf*16 + l15];
        }
        #pragma unroll
        for (int mf = 0; mf < 4; mf++){
            s16x8 a = lsA[kg*256 + wm*64 + mf*16 + l15];
            #pragma unroll
            for (int nf = 0; nf < 2; nf++){
                accg[mf][nf] = __builtin_amdgcn_mfma_f32_16x16x32_bf16(a, bg[nf], accg[mf][nf], 0, 0, 0);
                accu[mf][nf] = __builtin_amdgcn_mfma_f32_16x16x32_bf16(a, bu[nf], accu[mf][nf], 0, 0, 0);
            }
        }
    }
    #pragma unroll
    for (int mf = 0; mf < 4; mf++){
        #pragma unroll
        for (int j = 0; j < 4; j++){
            int row = m0 + wm*64 + mf*16 + kg*4 + j;
            if (row < cnt){
                #pragma unroll
                for (int nf = 0; nf < 2; nf++){
                    int col = n0 + wn*32 + nf*16 + l15;
                    float g = accg[mf][nf][j], u = accu[mf][nf][j];
                    float h = g / (1.f + expf(-g)) * u;
                    hact[(size_t)(off + row) * I_N + col] = f2bf(h);
                }
            }
        }
    }
}

// ---------------- GEMM2: 256x64 tile, 8 waves. out[tok] += w * (hact @ Wd^T) ----------------
__global__ __launch_bounds__(512) void gemm2_kernel(
    const short* __restrict__ hact,
    const float* __restrict__ Wd, const float* __restrict__ Wsd,
    const int* __restrict__ perm, const float* __restrict__ wgt,
    const int* __restrict__ ctrl, float* __restrict__ out)
{
    const int e   = blockIdx.y;
    const int cnt = ctrl[192 + e];
    const int m0  = blockIdx.x * BM;
    if (m0 >= cnt) return;
    const int off = ctrl[128 + e];
    const int n0  = blockIdx.z * 64;

    __shared__ s16x8 lsA[4*256];
    __shared__ s16x8 lsB[4*64];

    const int tid = threadIdx.x;
    const int r_a = tid & 255;
    const int kca = tid >> 8;
    const short* arow = nullptr;
    if (m0 + r_a < cnt) arow = hact + (size_t)(off + m0 + r_a) * I_N;

    const int cb  = tid & 255;
    const int kcb = cb & 3, rb = cb >> 2;
    const float* brow = (e < 32) ? (Wd  + ((size_t)e * H_N + (n0 + rb)) * I_N + kcb*8)
                                 : (Wsd + (size_t)(n0 + rb) * I_N + kcb*8);

    const int wid = tid >> 6, lane = tid & 63;
    const int wm = wid >> 1, wn = wid & 1;
    const int kg = lane >> 4, l15 = lane & 15;

    f32x4 acc[4][2];
    #pragma unroll
    for (int a = 0; a < 4; a++)
        #pragma unroll
        for (int b = 0; b < 2; b++)
            #pragma unroll
            for (int j = 0; j < 4; j++) acc[a][b][j] = 0.f;

    for (int k0 = 0; k0 < I_N; k0 += BK){
        s16x8 a0{}, a1{};
        if (arow){
            a0 = *(const s16x8*)(arow + k0 + kca*8);
            a1 = *(const s16x8*)(arow + k0 + (kca+2)*8);
        }
        float4 f0, f1;
        if (tid < 256){
            const float* p = brow + k0;
            f0 = *(const float4*)p;
            f1 = *(const float4*)(p + 4);
        }
        __syncthreads();
        lsA[kca*256 + r_a]     = a0;
        lsA[(kca+2)*256 + r_a] = a1;
        if (tid < 256) lsB[kcb*64 + rb] = cvt8(f0, f1);
        __syncthreads();
        s16x8 b[2];
        #pragma unroll
        for (int nf = 0; nf < 2; nf++)
            b[nf] = lsB[kg*64 + wn*32 + nf*16 + l15];
        #pragma unroll
        for (int mf = 0; mf < 4; mf++){
            s16x8 a = lsA[kg*256 + wm*64 + mf*16 + l15];
            #pragma unroll
            for (int nf = 0; nf < 2; nf++)
                acc[mf][nf] = __builtin_amdgcn_mfma_f32_16x16x32_bf16(a, b[nf], acc[mf][nf], 0, 0, 0);
        }
    }
    #pragma unroll
    for (int mf = 0; mf < 4; mf++){
        #pragma unroll
        for (int j = 0; j < 4; j++){
            int row = m0 + wm*64 + mf*16 + kg*4 + j;
            if (row < cnt){
                int aidx = off + row;
                int tok  = perm[aidx];
                float w  = wgt[aidx];
                #pragma unroll
                for (int nf = 0; nf < 2; nf++){
                    int col = n0 + wn*32 + nf*16 + l15;
                    atomicAdd(&out[(size_t)tok * H_N + col], w * acc[mf][nf][j]);
                }
            }
        }
    }
}

extern "C" void kernel_launch(void* const* d_in, const int* in_sizes, int n_in,
                              void* d_out, int out_size, void* d_ws, size_t ws_size,
                              hipStream_t stream)
{
    const float* x      = (const float*)d_in[0];
    const float* Wr     = (const float*)d_in[1];
    const float* Wg     = (const float*)d_in[2];
    const float* Wu     = (const float*)d_in[3];
    const float* Wd     = (const float*)d_in[4];
    const float* Wsg    = (const float*)d_in[5];
    const float* Wsu    = (const float*)d_in[6];
    const float* Wsd    = (const float*)d_in[7];
    const float* Wsgate = (const float*)d_in[8];

    float* out    = (float*)d_out;
    float* logits = out + (size_t)T_N * H_N;

    char* ws = (char*)d_ws;
    short* xbf  = (short*)ws;                    // 8,388,608 B
    short* hact = (short*)(ws + 8388608);        // 10,485,760 B
    int*   perm = (int*)(ws + 18874368);         // 40,960 B
    float* wgt  = (float*)(ws + 18915328);       // 40,960 B
    int*   tidx = (int*)(ws + 18956288);         // 32,768 B
    float* tw   = (float*)(ws + 18989056);       // 32,768 B
    int*   ctrl = (int*)(ws + 19021824);         // 1,024 B: counts[64]|cursor[64]|eoff[64]|ecnt[64]

    hipMemsetAsync(d_out, 0, (size_t)T_N * H_N * sizeof(float), stream);
    hipMemsetAsync(ctrl, 0, 256 * sizeof(int), stream);

    cast_x_kernel<<<2048, 256, 0, stream>>>(x, xbf);
    router_kernel<<<T_N, 64, 0, stream>>>(x, Wr, Wsgate, logits, tidx, tw, perm, wgt, ctrl);
    scan_kernel<<<1, 64, 0, stream>>>(ctrl);
    scatter_kernel<<<T_N/256, 256, 0, stream>>>(tidx, tw, perm, wgt, ctrl);
    gemm1_kernel<<<dim3(8, 33, 8),  512, 0, stream>>>(xbf, Wg, Wu, Wsg, Wsu, perm, ctrl, hact);
    gemm2_kernel<<<dim3(8, 33, 32), 512, 0, stream>>>(hact, Wd, Wsd, perm, wgt, ctrl, out);
}

// Round 3
// 450.191 us; speedup vs baseline: 3.2660x; 3.2660x over previous
//
#include <hip/hip_runtime.h>
#include <math.h>

#define T_N 2048
#define H_N 2048
#define E_N 32
#define I_N 512
#define NA_MOE (T_N*4)        // 8192 routed assignments
#define NA_ALL (NA_MOE + T_N) // + shared-expert rows = 10240
#define BM 256
#define BK 32
#define MAXT 72               // max m-tiles: sum ceil(cnt/256) <= 64 routed + 8 shared

typedef short s16x8 __attribute__((ext_vector_type(8)));
typedef float f32x4 __attribute__((ext_vector_type(4)));

__device__ inline short f2bf(float f){
    unsigned int u = __float_as_uint(f);
    u = (u + 0x7fffu + ((u >> 16) & 1u)) >> 16;
    return (short)u;
}

__device__ inline s16x8 cvt8(float4 f0, float4 f1){
    s16x8 v;
    v[0]=f2bf(f0.x); v[1]=f2bf(f0.y); v[2]=f2bf(f0.z); v[3]=f2bf(f0.w);
    v[4]=f2bf(f1.x); v[5]=f2bf(f1.y); v[6]=f2bf(f1.z); v[7]=f2bf(f1.w);
    return v;
}

// ---------------- cast x (fp32 -> bf16) ----------------
__global__ __launch_bounds__(256) void cast_x_kernel(const float* __restrict__ x,
                                                     short* __restrict__ xbf){
    size_t i = (size_t)(blockIdx.x * 256 + threadIdx.x) * 8;
    float4 a = *(const float4*)(x + i);
    float4 b = *(const float4*)(x + i + 4);
    *(s16x8*)(xbf + i) = cvt8(a, b);
}

// ---------------- router: logits (fp64 acc), softmax, top4, shared gate ----------------
__global__ __launch_bounds__(64) void router_kernel(
    const float* __restrict__ x, const float* __restrict__ Wr,
    const float* __restrict__ Wsgate,
    float* __restrict__ logits_out, int* __restrict__ tidx, float* __restrict__ tw,
    int* __restrict__ perm, float* __restrict__ wgt, int* __restrict__ counts)
{
    const int t = blockIdx.x, lane = threadIdx.x;
    const float* xr = x + (size_t)t * H_N;
    float xv[32];
    #pragma unroll
    for (int i = 0; i < 32; i++) xv[i] = xr[i*64 + lane];
    __shared__ float lg[34];
    for (int e = 0; e < 33; e++){
        const float* wr = (e < 32) ? (Wr + (size_t)e * H_N) : Wsgate;
        double s = 0.0;
        #pragma unroll
        for (int i = 0; i < 32; i++) s += (double)xv[i] * (double)wr[i*64 + lane];
        #pragma unroll
        for (int o = 32; o > 0; o >>= 1) s += __shfl_down(s, o);
        if (lane == 0) lg[e] = (float)s;
    }
    __syncthreads();
    if (lane < 32) logits_out[(size_t)t*32 + lane] = lg[lane];
    if (lane == 0){
        float m = lg[0];
        for (int e = 1; e < 32; e++) m = fmaxf(m, lg[e]);
        unsigned mask = 0; int sel[4]; float sv[4]; float s4 = 0.f;
        for (int k = 0; k < 4; k++){
            int best = -1; float bv = -1e30f;
            for (int e = 0; e < 32; e++)
                if (!((mask >> e) & 1u) && lg[e] > bv){ bv = lg[e]; best = e; }
            mask |= 1u << best; sel[k] = best;
            float p = expf(lg[best] - m); sv[k] = p; s4 += p;
        }
        for (int k = 0; k < 4; k++){
            tidx[t*4 + k] = sel[k];
            tw[t*4 + k]   = sv[k] / s4;
            atomicAdd(&counts[sel[k]], 1);
        }
        perm[NA_MOE + t] = t;                       // shared expert row
        wgt[NA_MOE + t]  = 1.f / (1.f + expf(-lg[32]));
    }
}

// ---------------- scan: offsets + worklist ----------------
// ctrl layout (ints): [0..63] counts, [64..127] cursors, [128..191] eoff,
//                     [192..255] ecnt, [256] ntiles, [260..331] worklist
__global__ void scan_kernel(int* ctrl){
    if (threadIdx.x == 0){
        int* counts = ctrl; int* eoff = ctrl + 128; int* ecnt = ctrl + 192;
        int acc = 0;
        for (int e = 0; e < 32; e++){ eoff[e] = acc; ecnt[e] = counts[e]; acc += counts[e]; }
        eoff[32] = NA_MOE; ecnt[32] = T_N;
        int nt = 0;
        for (int e = 0; e < 33; e++){
            int c = ecnt[e];
            for (int m = 0; m * BM < c; m++) ctrl[260 + nt++] = (e << 16) | m;
        }
        ctrl[256] = nt;
    }
    if (threadIdx.x < 64) ctrl[64 + threadIdx.x] = 0;  // cursors
}

// ---------------- scatter tokens into per-expert lists ----------------
__global__ __launch_bounds__(256) void scatter_kernel(
    const int* __restrict__ tidx, const float* __restrict__ tw,
    int* __restrict__ perm, float* __restrict__ wgt, int* ctrl)
{
    int t = blockIdx.x * 256 + threadIdx.x;
    if (t >= T_N) return;
    const int* eoff = ctrl + 128; int* cursor = ctrl + 64;
    for (int k = 0; k < 4; k++){
        int e = tidx[t*4 + k];
        int pos = eoff[e] + atomicAdd(&cursor[e], 1);
        perm[pos] = t; wgt[pos] = tw[t*4 + k];
    }
}

// ---------------- GEMM1: worklist-driven 256x64 tile, 8 waves, reg-prefetch ----------------
__global__ __launch_bounds__(512) void gemm1_kernel(
    const short* __restrict__ xbf,
    const float* __restrict__ Wg, const float* __restrict__ Wu,
    const float* __restrict__ Wsg, const float* __restrict__ Wsu,
    const int* __restrict__ perm, const int* __restrict__ ctrl,
    short* __restrict__ hact)
{
    const int tile = blockIdx.x >> 3;
    if (tile >= ctrl[256]) return;
    const int wrk = ctrl[260 + tile];
    const int e   = wrk >> 16;
    const int m0  = (wrk & 0xffff) << 8;
    const int cnt = ctrl[192 + e];
    const int off = ctrl[128 + e];
    const int n0  = (blockIdx.x & 7) << 6;

    __shared__ s16x8 lsA[4*256];   // [kc][row]
    __shared__ s16x8 lsBg[4*64];
    __shared__ s16x8 lsBu[4*64];

    const int tid = threadIdx.x;
    const int r_a = tid & 255;
    const int kca = tid >> 8;      // 0/1 (owns chunks kca, kca+2)
    const short* arow = nullptr;
    if (m0 + r_a < cnt) arow = xbf + (size_t)perm[off + m0 + r_a] * H_N;

    const int cb  = tid & 255;
    const int kcb = cb & 3, rb = cb >> 2;
    const float* brow;
    if (e < 32){
        const float* Wbase = (tid < 256) ? Wg : Wu;
        brow = Wbase + ((size_t)e * I_N + (n0 + rb)) * H_N + kcb*8;
    } else {
        const float* Wbase = (tid < 256) ? Wsg : Wsu;
        brow = Wbase + (size_t)(n0 + rb) * H_N + kcb*8;
    }
    s16x8* lsBmine = (tid < 256) ? lsBg : lsBu;

    const int wid = tid >> 6, lane = tid & 63;
    const int wm = wid >> 1, wn = wid & 1;       // 4m x 2n waves
    const int kg = lane >> 4, l15 = lane & 15;

    f32x4 accg[4][2], accu[4][2];
    #pragma unroll
    for (int a = 0; a < 4; a++)
        #pragma unroll
        for (int b = 0; b < 2; b++)
            #pragma unroll
            for (int j = 0; j < 4; j++){ accg[a][b][j] = 0.f; accu[a][b][j] = 0.f; }

    // prologue: load k0=0 into regs
    s16x8 a0{}, a1{};
    float4 f0, f1;
    if (arow){
        a0 = *(const s16x8*)(arow + kca*8);
        a1 = *(const s16x8*)(arow + (kca+2)*8);
    }
    f0 = *(const float4*)(brow);
    f1 = *(const float4*)(brow + 4);

    for (int k0 = 0; k0 < H_N; k0 += BK){
        __syncthreads();
        lsA[kca*256 + r_a]     = a0;
        lsA[(kca+2)*256 + r_a] = a1;
        lsBmine[kcb*64 + rb]   = cvt8(f0, f1);
        __syncthreads();
        if (k0 + BK < H_N){                       // prefetch next k-step
            if (arow){
                a0 = *(const s16x8*)(arow + k0 + BK + kca*8);
                a1 = *(const s16x8*)(arow + k0 + BK + (kca+2)*8);
            }
            f0 = *(const float4*)(brow + k0 + BK);
            f1 = *(const float4*)(brow + k0 + BK + 4);
        }
        s16x8 bg[2], bu[2];
        #pragma unroll
        for (int nf = 0; nf < 2; nf++){
            bg[nf] = lsBg[kg*64 + wn*32 + nf*16 + l15];
            bu[nf] = lsBu[kg*64 + wn*32 + nf*16 + l15];
        }
        #pragma unroll
        for (int mf = 0; mf < 4; mf++){
            s16x8 a = lsA[kg*256 + wm*64 + mf*16 + l15];
            #pragma unroll
            for (int nf = 0; nf < 2; nf++){
                accg[mf][nf] = __builtin_amdgcn_mfma_f32_16x16x32_bf16(a, bg[nf], accg[mf][nf], 0, 0, 0);
                accu[mf][nf] = __builtin_amdgcn_mfma_f32_16x16x32_bf16(a, bu[nf], accu[mf][nf], 0, 0, 0);
            }
        }
    }
    #pragma unroll
    for (int mf = 0; mf < 4; mf++){
        #pragma unroll
        for (int j = 0; j < 4; j++){
            int row = m0 + wm*64 + mf*16 + kg*4 + j;
            if (row < cnt){
                #pragma unroll
                for (int nf = 0; nf < 2; nf++){
                    int col = n0 + wn*32 + nf*16 + l15;
                    float g = accg[mf][nf][j], u = accu[mf][nf][j];
                    float h = g / (1.f + expf(-g)) * u;
                    hact[(size_t)(off + row) * I_N + col] = f2bf(h);
                }
            }
        }
    }
}

// ---------------- GEMM2: worklist-driven 256x64 tile, reg-prefetch, atomic combine ----------------
__global__ __launch_bounds__(512) void gemm2_kernel(
    const short* __restrict__ hact,
    const float* __restrict__ Wd, const float* __restrict__ Wsd,
    const int* __restrict__ perm, const float* __restrict__ wgt,
    const int* __restrict__ ctrl, float* __restrict__ out)
{
    const int tile = blockIdx.x >> 5;
    if (tile >= ctrl[256]) return;
    const int wrk = ctrl[260 + tile];
    const int e   = wrk >> 16;
    const int m0  = (wrk & 0xffff) << 8;
    const int cnt = ctrl[192 + e];
    const int off = ctrl[128 + e];
    const int n0  = (blockIdx.x & 31) << 6;

    __shared__ s16x8 lsA[4*256];
    __shared__ s16x8 lsB[4*64];

    const int tid = threadIdx.x;
    const int r_a = tid & 255;
    const int kca = tid >> 8;
    const short* arow = nullptr;
    if (m0 + r_a < cnt) arow = hact + (size_t)(off + m0 + r_a) * I_N;

    const int cb  = tid & 255;
    const int kcb = cb & 3, rb = cb >> 2;
    const float* brow = (e < 32) ? (Wd  + ((size_t)e * H_N + (n0 + rb)) * I_N + kcb*8)
                                 : (Wsd + (size_t)(n0 + rb) * I_N + kcb*8);

    const int wid = tid >> 6, lane = tid & 63;
    const int wm = wid >> 1, wn = wid & 1;
    const int kg = lane >> 4, l15 = lane & 15;

    f32x4 acc[4][2];
    #pragma unroll
    for (int a = 0; a < 4; a++)
        #pragma unroll
        for (int b = 0; b < 2; b++)
            #pragma unroll
            for (int j = 0; j < 4; j++) acc[a][b][j] = 0.f;

    s16x8 a0{}, a1{};
    float4 f0, f1;
    if (arow){
        a0 = *(const s16x8*)(arow + kca*8);
        a1 = *(const s16x8*)(arow + (kca+2)*8);
    }
    if (tid < 256){
        f0 = *(const float4*)(brow);
        f1 = *(const float4*)(brow + 4);
    }

    for (int k0 = 0; k0 < I_N; k0 += BK){
        __syncthreads();
        lsA[kca*256 + r_a]     = a0;
        lsA[(kca+2)*256 + r_a] = a1;
        if (tid < 256) lsB[kcb*64 + rb] = cvt8(f0, f1);
        __syncthreads();
        if (k0 + BK < I_N){
            if (arow){
                a0 = *(const s16x8*)(arow + k0 + BK + kca*8);
                a1 = *(const s16x8*)(arow + k0 + BK + (kca+2)*8);
            }
            if (tid < 256){
                f0 = *(const float4*)(brow + k0 + BK);
                f1 = *(const float4*)(brow + k0 + BK + 4);
            }
        }
        s16x8 b[2];
        #pragma unroll
        for (int nf = 0; nf < 2; nf++)
            b[nf] = lsB[kg*64 + wn*32 + nf*16 + l15];
        #pragma unroll
        for (int mf = 0; mf < 4; mf++){
            s16x8 a = lsA[kg*256 + wm*64 + mf*16 + l15];
            #pragma unroll
            for (int nf = 0; nf < 2; nf++)
                acc[mf][nf] = __builtin_amdgcn_mfma_f32_16x16x32_bf16(a, b[nf], acc[mf][nf], 0, 0, 0);
        }
    }
    #pragma unroll
    for (int mf = 0; mf < 4; mf++){
        #pragma unroll
        for (int j = 0; j < 4; j++){
            int row = m0 + wm*64 + mf*16 + kg*4 + j;
            if (row < cnt){
                int aidx = off + row;
                int tok  = perm[aidx];
                float w  = wgt[aidx];
                #pragma unroll
                for (int nf = 0; nf < 2; nf++){
                    int col = n0 + wn*32 + nf*16 + l15;
                    atomicAdd(&out[(size_t)tok * H_N + col], w * acc[mf][nf][j]);
                }
            }
        }
    }
}

extern "C" void kernel_launch(void* const* d_in, const int* in_sizes, int n_in,
                              void* d_out, int out_size, void* d_ws, size_t ws_size,
                              hipStream_t stream)
{
    const float* x      = (const float*)d_in[0];
    const float* Wr     = (const float*)d_in[1];
    const float* Wg     = (const float*)d_in[2];
    const float* Wu     = (const float*)d_in[3];
    const float* Wd     = (const float*)d_in[4];
    const float* Wsg    = (const float*)d_in[5];
    const float* Wsu    = (const float*)d_in[6];
    const float* Wsd    = (const float*)d_in[7];
    const float* Wsgate = (const float*)d_in[8];

    float* out    = (float*)d_out;
    float* logits = out + (size_t)T_N * H_N;

    char* ws = (char*)d_ws;
    short* xbf  = (short*)ws;                    // 8,388,608 B
    short* hact = (short*)(ws + 8388608);        // 10,485,760 B
    int*   perm = (int*)(ws + 18874368);         // 40,960 B
    float* wgt  = (float*)(ws + 18915328);       // 40,960 B
    int*   tidx = (int*)(ws + 18956288);         // 32,768 B
    float* tw   = (float*)(ws + 18989056);       // 32,768 B
    int*   ctrl = (int*)(ws + 19021824);         // 2,048 B

    hipMemsetAsync(d_out, 0, (size_t)T_N * H_N * sizeof(float), stream);
    hipMemsetAsync(ctrl, 0, 256 * sizeof(int), stream);

    cast_x_kernel<<<2048, 256, 0, stream>>>(x, xbf);
    router_kernel<<<T_N, 64, 0, stream>>>(x, Wr, Wsgate, logits, tidx, tw, perm, wgt, ctrl);
    scan_kernel<<<1, 64, 0, stream>>>(ctrl);
    scatter_kernel<<<T_N/256, 256, 0, stream>>>(tidx, tw, perm, wgt, ctrl);
    gemm1_kernel<<<MAXT*8,  512, 0, stream>>>(xbf, Wg, Wu, Wsg, Wsu, perm, ctrl, hact);
    gemm2_kernel<<<MAXT*32, 512, 0, stream>>>(hact, Wd, Wsd, perm, wgt, ctrl, out);
}

// Round 4
// 363.762 us; speedup vs baseline: 4.0420x; 1.2376x over previous
//
#include <hip/hip_runtime.h>
#include <math.h>

#define T_N 2048
#define H_N 2048
#define E_N 32
#define I_N 512
#define NA_MOE (T_N*4)        // 8192 routed assignments
#define NA_ALL (NA_MOE + T_N) // + shared-expert rows = 10240
#define BM 128
#define BK 32
#define MAXT 112              // max m-tiles: 64 full + 32 partial routed + 16 shared

typedef short s16x8 __attribute__((ext_vector_type(8)));
typedef float f32x4 __attribute__((ext_vector_type(4)));

__device__ inline short f2bf(float f){
    unsigned int u = __float_as_uint(f);
    u = (u + 0x7fffu + ((u >> 16) & 1u)) >> 16;
    return (short)u;
}
__device__ inline float bf2f(short s){
    return __uint_as_float(((unsigned int)(unsigned short)s) << 16);
}
__device__ inline s16x8 cvt8(float4 f0, float4 f1){
    s16x8 v;
    v[0]=f2bf(f0.x); v[1]=f2bf(f0.y); v[2]=f2bf(f0.z); v[3]=f2bf(f0.w);
    v[4]=f2bf(f1.x); v[5]=f2bf(f1.y); v[6]=f2bf(f1.z); v[7]=f2bf(f1.w);
    return v;
}

// ---------------- cast x (fp32 -> bf16) ----------------
__global__ __launch_bounds__(256) void cast_x_kernel(const float* __restrict__ x,
                                                     short* __restrict__ xbf){
    size_t i = (size_t)(blockIdx.x * 256 + threadIdx.x) * 8;
    float4 a = *(const float4*)(x + i);
    float4 b = *(const float4*)(x + i + 4);
    *(s16x8*)(xbf + i) = cvt8(a, b);
}

// ---------------- router: logits (fp64 acc), softmax, top4, shared gate ----------------
__global__ __launch_bounds__(64) void router_kernel(
    const float* __restrict__ x, const float* __restrict__ Wr,
    const float* __restrict__ Wsgate,
    float* __restrict__ logits_out, int* __restrict__ tidx, float* __restrict__ tw,
    int* __restrict__ perm, float* __restrict__ wgt, int* __restrict__ counts)
{
    const int t = blockIdx.x, lane = threadIdx.x;
    const float* xr = x + (size_t)t * H_N;
    float xv[32];
    #pragma unroll
    for (int i = 0; i < 32; i++) xv[i] = xr[i*64 + lane];
    __shared__ float lg[34];
    for (int e = 0; e < 33; e++){
        const float* wr = (e < 32) ? (Wr + (size_t)e * H_N) : Wsgate;
        double s = 0.0;
        #pragma unroll
        for (int i = 0; i < 32; i++) s += (double)xv[i] * (double)wr[i*64 + lane];
        #pragma unroll
        for (int o = 32; o > 0; o >>= 1) s += __shfl_down(s, o);
        if (lane == 0) lg[e] = (float)s;
    }
    __syncthreads();
    if (lane < 32) logits_out[(size_t)t*32 + lane] = lg[lane];
    if (lane == 0){
        float m = lg[0];
        for (int e = 1; e < 32; e++) m = fmaxf(m, lg[e]);
        unsigned mask = 0; int sel[4]; float sv[4]; float s4 = 0.f;
        for (int k = 0; k < 4; k++){
            int best = -1; float bv = -1e30f;
            for (int e = 0; e < 32; e++)
                if (!((mask >> e) & 1u) && lg[e] > bv){ bv = lg[e]; best = e; }
            mask |= 1u << best; sel[k] = best;
            float p = expf(lg[best] - m); sv[k] = p; s4 += p;
        }
        for (int k = 0; k < 4; k++){
            tidx[t*4 + k] = sel[k];
            tw[t*4 + k]   = sv[k] / s4;
            atomicAdd(&counts[sel[k]], 1);
        }
        perm[NA_MOE + t] = t;                       // shared expert row
        wgt[NA_MOE + t]  = 1.f / (1.f + expf(-lg[32]));
    }
}

// ---------------- scan: offsets + worklist ----------------
// ctrl ints: [0..63] counts, [64..127] cursors, [128..191] eoff,
//            [192..255] ecnt, [256] ntiles, [260..371] worklist
__global__ void scan_kernel(int* ctrl){
    if (threadIdx.x == 0){
        int* counts = ctrl; int* eoff = ctrl + 128; int* ecnt = ctrl + 192;
        int acc = 0;
        for (int e = 0; e < 32; e++){ eoff[e] = acc; ecnt[e] = counts[e]; acc += counts[e]; }
        eoff[32] = NA_MOE; ecnt[32] = T_N;
        int nt = 0;
        for (int e = 0; e < 33; e++){
            int c = ecnt[e];
            for (int m = 0; m * BM < c; m++) ctrl[260 + nt++] = (e << 16) | m;
        }
        ctrl[256] = nt;
    }
    if (threadIdx.x < 64) ctrl[64 + threadIdx.x] = 0;  // cursors
}

// ---------------- scatter tokens into per-expert lists ----------------
__global__ __launch_bounds__(256) void scatter_kernel(
    const int* __restrict__ tidx, const float* __restrict__ tw,
    int* __restrict__ perm, float* __restrict__ wgt, int* __restrict__ apos,
    int* ctrl)
{
    int t = blockIdx.x * 256 + threadIdx.x;
    if (t >= T_N) return;
    const int* eoff = ctrl + 128; int* cursor = ctrl + 64;
    for (int k = 0; k < 4; k++){
        int e = tidx[t*4 + k];
        int pos = eoff[e] + atomicAdd(&cursor[e], 1);
        perm[pos] = t; wgt[pos] = tw[t*4 + k]; apos[t*4 + k] = pos;
    }
}

// ---------------- GEMM1: worklist 128x64 tile, 4 waves, reg-prefetch ----------------
__global__ __launch_bounds__(256, 3) void gemm1_kernel(
    const short* __restrict__ xbf,
    const float* __restrict__ Wg, const float* __restrict__ Wu,
    const float* __restrict__ Wsg, const float* __restrict__ Wsu,
    const int* __restrict__ perm, const int* __restrict__ ctrl,
    short* __restrict__ hact)
{
    const int tile = blockIdx.x >> 3;
    if (tile >= ctrl[256]) return;
    const int wrk = ctrl[260 + tile];
    const int e   = wrk >> 16;
    const int m0  = (wrk & 0xffff) << 7;
    const int cnt = ctrl[192 + e];
    const int off = ctrl[128 + e];
    const int n0  = (blockIdx.x & 7) << 6;

    __shared__ s16x8 lsA[4*128];   // [kc][row]
    __shared__ s16x8 lsBg[4*64];
    __shared__ s16x8 lsBu[4*64];

    const int tid = threadIdx.x;
    // A staging: row r_a, chunks kca and kca+2
    const int r_a = tid & 127;
    const int kca = tid >> 7;      // 0/1
    const short* arow = nullptr;
    if (m0 + r_a < cnt) arow = xbf + (size_t)perm[off + m0 + r_a] * H_N;

    // B staging: every thread stages one chunk of g AND one of u
    const int rb = tid >> 2, kcb = tid & 3;
    const float *browg, *browu;
    if (e < 32){
        browg = Wg + ((size_t)e * I_N + (n0 + rb)) * H_N + kcb*8;
        browu = Wu + ((size_t)e * I_N + (n0 + rb)) * H_N + kcb*8;
    } else {
        browg = Wsg + (size_t)(n0 + rb) * H_N + kcb*8;
        browu = Wsu + (size_t)(n0 + rb) * H_N + kcb*8;
    }

    const int wid = tid >> 6, lane = tid & 63;
    const int wm = wid >> 1, wn = wid & 1;       // 2m x 2n waves
    const int kg = lane >> 4, l15 = lane & 15;

    f32x4 accg[4][2], accu[4][2];
    #pragma unroll
    for (int a = 0; a < 4; a++)
        #pragma unroll
        for (int b = 0; b < 2; b++)
            #pragma unroll
            for (int j = 0; j < 4; j++){ accg[a][b][j] = 0.f; accu[a][b][j] = 0.f; }

    // prologue: load k0=0 into regs
    s16x8 a0{}, a1{};
    if (arow){
        a0 = *(const s16x8*)(arow + kca*8);
        a1 = *(const s16x8*)(arow + (kca+2)*8);
    }
    float4 g0 = *(const float4*)(browg);
    float4 g1 = *(const float4*)(browg + 4);
    float4 u0 = *(const float4*)(browu);
    float4 u1 = *(const float4*)(browu + 4);

    for (int k0 = 0; k0 < H_N; k0 += BK){
        __syncthreads();
        lsA[kca*128 + r_a]     = a0;
        lsA[(kca+2)*128 + r_a] = a1;
        lsBg[kcb*64 + rb]      = cvt8(g0, g1);
        lsBu[kcb*64 + rb]      = cvt8(u0, u1);
        __syncthreads();
        if (k0 + BK < H_N){                       // prefetch next k-step
            if (arow){
                a0 = *(const s16x8*)(arow + k0 + BK + kca*8);
                a1 = *(const s16x8*)(arow + k0 + BK + (kca+2)*8);
            }
            g0 = *(const float4*)(browg + k0 + BK);
            g1 = *(const float4*)(browg + k0 + BK + 4);
            u0 = *(const float4*)(browu + k0 + BK);
            u1 = *(const float4*)(browu + k0 + BK + 4);
        }
        #pragma unroll
        for (int mf = 0; mf < 4; mf++){
            s16x8 a = lsA[kg*128 + wm*64 + mf*16 + l15];
            #pragma unroll
            for (int nf = 0; nf < 2; nf++){
                s16x8 bg = lsBg[kg*64 + wn*32 + nf*16 + l15];
                s16x8 bu = lsBu[kg*64 + wn*32 + nf*16 + l15];
                accg[mf][nf] = __builtin_amdgcn_mfma_f32_16x16x32_bf16(a, bg, accg[mf][nf], 0, 0, 0);
                accu[mf][nf] = __builtin_amdgcn_mfma_f32_16x16x32_bf16(a, bu, accu[mf][nf], 0, 0, 0);
            }
        }
    }
    #pragma unroll
    for (int mf = 0; mf < 4; mf++){
        #pragma unroll
        for (int j = 0; j < 4; j++){
            int row = m0 + wm*64 + mf*16 + kg*4 + j;
            if (row < cnt){
                #pragma unroll
                for (int nf = 0; nf < 2; nf++){
                    int col = n0 + wn*32 + nf*16 + l15;
                    float g = accg[mf][nf][j], u = accu[mf][nf][j];
                    float h = g / (1.f + expf(-g)) * u;
                    hact[(size_t)(off + row) * I_N + col] = f2bf(h);
                }
            }
        }
    }
}

// ---------------- GEMM2: worklist 128x64 tile, 4 waves, reg-prefetch ----------------
template<int USE_Y>
__global__ __launch_bounds__(256) void gemm2_kernel(
    const short* __restrict__ hact,
    const float* __restrict__ Wd, const float* __restrict__ Wsd,
    const int* __restrict__ perm, const float* __restrict__ wgt,
    const int* __restrict__ ctrl, float* __restrict__ out, short* __restrict__ y)
{
    const int tile = blockIdx.x >> 5;
    if (tile >= ctrl[256]) return;
    const int wrk = ctrl[260 + tile];
    const int e   = wrk >> 16;
    const int m0  = (wrk & 0xffff) << 7;
    const int cnt = ctrl[192 + e];
    const int off = ctrl[128 + e];
    const int n0  = (blockIdx.x & 31) << 6;

    __shared__ s16x8 lsA[4*128];
    __shared__ s16x8 lsB[4*64];

    const int tid = threadIdx.x;
    const int r_a = tid & 127;
    const int kca = tid >> 7;
    const short* arow = nullptr;
    if (m0 + r_a < cnt) arow = hact + (size_t)(off + m0 + r_a) * I_N;

    const int rb = tid >> 2, kcb = tid & 3;
    const float* brow = (e < 32) ? (Wd  + ((size_t)e * H_N + (n0 + rb)) * I_N + kcb*8)
                                 : (Wsd + (size_t)(n0 + rb) * I_N + kcb*8);

    const int wid = tid >> 6, lane = tid & 63;
    const int wm = wid >> 1, wn = wid & 1;
    const int kg = lane >> 4, l15 = lane & 15;

    f32x4 acc[4][2];
    #pragma unroll
    for (int a = 0; a < 4; a++)
        #pragma unroll
        for (int b = 0; b < 2; b++)
            #pragma unroll
            for (int j = 0; j < 4; j++) acc[a][b][j] = 0.f;

    s16x8 a0{}, a1{};
    if (arow){
        a0 = *(const s16x8*)(arow + kca*8);
        a1 = *(const s16x8*)(arow + (kca+2)*8);
    }
    float4 f0 = *(const float4*)(brow);
    float4 f1 = *(const float4*)(brow + 4);

    for (int k0 = 0; k0 < I_N; k0 += BK){
        __syncthreads();
        lsA[kca*128 + r_a]     = a0;
        lsA[(kca+2)*128 + r_a] = a1;
        lsB[kcb*64 + rb]       = cvt8(f0, f1);
        __syncthreads();
        if (k0 + BK < I_N){
            if (arow){
                a0 = *(const s16x8*)(arow + k0 + BK + kca*8);
                a1 = *(const s16x8*)(arow + k0 + BK + (kca+2)*8);
            }
            f0 = *(const float4*)(brow + k0 + BK);
            f1 = *(const float4*)(brow + k0 + BK + 4);
        }
        #pragma unroll
        for (int mf = 0; mf < 4; mf++){
            s16x8 a = lsA[kg*128 + wm*64 + mf*16 + l15];
            #pragma unroll
            for (int nf = 0; nf < 2; nf++){
                s16x8 b = lsB[kg*64 + wn*32 + nf*16 + l15];
                acc[mf][nf] = __builtin_amdgcn_mfma_f32_16x16x32_bf16(a, b, acc[mf][nf], 0, 0, 0);
            }
        }
    }
    #pragma unroll
    for (int mf = 0; mf < 4; mf++){
        #pragma unroll
        for (int j = 0; j < 4; j++){
            int row = m0 + wm*64 + mf*16 + kg*4 + j;
            if (row < cnt){
                int aidx = off + row;
                if (USE_Y){
                    #pragma unroll
                    for (int nf = 0; nf < 2; nf++){
                        int col = n0 + wn*32 + nf*16 + l15;
                        y[(size_t)aidx * H_N + col] = f2bf(acc[mf][nf][j]);
                    }
                } else {
                    int tok = perm[aidx];
                    float w = wgt[aidx];
                    #pragma unroll
                    for (int nf = 0; nf < 2; nf++){
                        int col = n0 + wn*32 + nf*16 + l15;
                        atomicAdd(&out[(size_t)tok * H_N + col], w * acc[mf][nf][j]);
                    }
                }
            }
        }
    }
}

// ---------------- combine: out[t] = sum_k w*y[apos] + sig*y[shared] ----------------
__global__ __launch_bounds__(256) void combine_kernel(
    const short* __restrict__ y, const int* __restrict__ apos,
    const float* __restrict__ tw, const float* __restrict__ wgt,
    float* __restrict__ out)
{
    const int t = blockIdx.x;
    const int c0 = threadIdx.x * 8;
    float acc[8];
    {
        float ws = wgt[NA_MOE + t];
        s16x8 v = *(const s16x8*)(y + (size_t)(NA_MOE + t) * H_N + c0);
        #pragma unroll
        for (int j = 0; j < 8; j++) acc[j] = ws * bf2f(v[j]);
    }
    #pragma unroll
    for (int k = 0; k < 4; k++){
        int p   = apos[t*4 + k];
        float w = tw[t*4 + k];
        s16x8 v = *(const s16x8*)(y + (size_t)p * H_N + c0);
        #pragma unroll
        for (int j = 0; j < 8; j++) acc[j] += w * bf2f(v[j]);
    }
    float4 o0 = make_float4(acc[0], acc[1], acc[2], acc[3]);
    float4 o1 = make_float4(acc[4], acc[5], acc[6], acc[7]);
    *(float4*)(out + (size_t)t * H_N + c0)     = o0;
    *(float4*)(out + (size_t)t * H_N + c0 + 4) = o1;
}

extern "C" void kernel_launch(void* const* d_in, const int* in_sizes, int n_in,
                              void* d_out, int out_size, void* d_ws, size_t ws_size,
                              hipStream_t stream)
{
    const float* x      = (const float*)d_in[0];
    const float* Wr     = (const float*)d_in[1];
    const float* Wg     = (const float*)d_in[2];
    const float* Wu     = (const float*)d_in[3];
    const float* Wd     = (const float*)d_in[4];
    const float* Wsg    = (const float*)d_in[5];
    const float* Wsu    = (const float*)d_in[6];
    const float* Wsd    = (const float*)d_in[7];
    const float* Wsgate = (const float*)d_in[8];

    float* out    = (float*)d_out;
    float* logits = out + (size_t)T_N * H_N;

    char* ws = (char*)d_ws;
    short* xbf  = (short*)ws;                          // 8,388,608 B
    short* hact = (short*)(ws + 8388608);              // 10,485,760 B
    int*   perm = (int*)(ws + 18874368);               // 40,960
    float* wgt  = (float*)(ws + 18915328);             // 40,960
    int*   tidx = (int*)(ws + 18956288);               // 32,768
    float* tw   = (float*)(ws + 18989056);             // 32,768
    int*   apos = (int*)(ws + 19021824);               // 32,768
    int*   ctrl = (int*)(ws + 19054592);               // 2,048
    short* y    = (short*)(ws + 19056640);             // 41,943,040
    const size_t Y_END = 19056640ull + 41943040ull;
    const bool use_y = (ws_size >= Y_END);

    hipMemsetAsync(ctrl, 0, 256 * sizeof(int), stream);
    if (!use_y)
        hipMemsetAsync(d_out, 0, (size_t)T_N * H_N * sizeof(float), stream);

    cast_x_kernel<<<2048, 256, 0, stream>>>(x, xbf);
    router_kernel<<<T_N, 64, 0, stream>>>(x, Wr, Wsgate, logits, tidx, tw, perm, wgt, ctrl);
    scan_kernel<<<1, 64, 0, stream>>>(ctrl);
    scatter_kernel<<<T_N/256, 256, 0, stream>>>(tidx, tw, perm, wgt, apos, ctrl);
    gemm1_kernel<<<MAXT*8, 256, 0, stream>>>(xbf, Wg, Wu, Wsg, Wsu, perm, ctrl, hact);
    if (use_y){
        gemm2_kernel<1><<<MAXT*32, 256, 0, stream>>>(hact, Wd, Wsd, perm, wgt, ctrl, out, y);
        combine_kernel<<<T_N, 256, 0, stream>>>(y, apos, tw, wgt, out);
    } else {
        gemm2_kernel<0><<<MAXT*32, 256, 0, stream>>>(hact, Wd, Wsd, perm, wgt, ctrl, out, y);
    }
}